// Round 5
// baseline (914.728 us; speedup 1.0000x reference)
//
#include <hip/hip_runtime.h>
#include <cstdint>
#include <cstddef>

#define ND 256          // embedding dim
#define NK 4096         // num codes
#define NROWS 65536     // 32*2048
#define M_OUT 16777216  // NROWS*ND
#define IDX_OFF (M_OUT + 4)

// ---------------- workspace layout (bytes) ----------------
#define WS_INV64   0                         // double[65536]  512KB
#define WS_E2_64   (512*1024)                // double[4096]   32KB
#define WS_E2_32   (WS_E2_64 + 32*1024)      // float[4096]    16KB
#define WS_EH      (WS_E2_32 + 16*1024)      // f16[1M]        2MB
#define WS_BESTIDX (WS_EH + 2*1024*1024)     // int[65536]     256KB
#define WS_COUNTS  (WS_BESTIDX + 256*1024)   // int[4096]      16KB
#define WS_RCOUNT  (WS_COUNTS + 16*1024)     // int[1] + pad   16B
#define WS_RROWS   (WS_RCOUNT + 16)          // int[65536]     256KB
#define WS_RCNT2   (WS_RROWS + 256*1024)     // int[1] + pad   16B
#define WS_RROWS2  (WS_RCNT2 + 16)           // int[4096]      16KB
#define WS_KEYS    (WS_RROWS2 + 16*1024)     // u64[4096]      32KB
#define WS_PART    (WS_KEYS + 32*1024)       // double[16384]  128KB

typedef _Float16 f16x8 __attribute__((ext_vector_type(8)));
typedef _Float16 f16x4v __attribute__((ext_vector_type(4)));
typedef __attribute__((ext_vector_type(4))) float f32x4;

// async 16B global->LDS (direct-to-shared DMA); lds dest must be wave-uniform base
__device__ __forceinline__ void gll16(const void* g, void* l) {
  __builtin_amdgcn_global_load_lds(
      (const __attribute__((address_space(1))) unsigned int*)g,
      (__attribute__((address_space(3))) unsigned int*)l, 16, 0, 0);
}

// ---------------- kernel 1: row norms + normalized fp16 plane ----------------
__global__ void rownorm_k(const float* __restrict__ z, double* __restrict__ inv64,
                          unsigned short* __restrict__ zh) {
  const int w = threadIdx.x >> 6, lane = threadIdx.x & 63;
  const int row = blockIdx.x * 4 + w;
  const float4 v = *reinterpret_cast<const float4*>(z + (size_t)row * ND + lane * 4);
  double s = (double)v.x * v.x + (double)v.y * v.y + (double)v.z * v.z + (double)v.w * v.w;
  #pragma unroll
  for (int m = 32; m; m >>= 1) s += __shfl_xor(s, m, 64);
  double nrm = sqrt(s);
  if (nrm < 1e-12) nrm = 1e-12;
  const double inv = 1.0 / nrm;
  if (lane == 0) inv64[row] = inv;
  f16x4v h;
  h[0] = (_Float16)(float)(v.x * inv);
  h[1] = (_Float16)(float)(v.y * inv);
  h[2] = (_Float16)(float)(v.z * inv);
  h[3] = (_Float16)(float)(v.w * inv);
  *reinterpret_cast<f16x4v*>(reinterpret_cast<_Float16*>(zh) + (size_t)row * ND + lane * 4) = h;
}

// ---------------- kernel 2: code norms (fp64 + fp32) + fp16 plane ----------------
__global__ void embnorm_k(const float* __restrict__ e, double* __restrict__ e2_64,
                          float* __restrict__ e2_32, unsigned short* __restrict__ eh) {
  const int w = threadIdx.x >> 6, lane = threadIdx.x & 63;
  const int row = blockIdx.x * 4 + w;
  const float4 v = *reinterpret_cast<const float4*>(e + (size_t)row * ND + lane * 4);
  double s = (double)v.x * v.x + (double)v.y * v.y + (double)v.z * v.z + (double)v.w * v.w;
  #pragma unroll
  for (int m = 32; m; m >>= 1) s += __shfl_xor(s, m, 64);
  if (lane == 0) { e2_64[row] = s; e2_32[row] = (float)s; }
  f16x4v h;
  h[0] = (_Float16)v.x; h[1] = (_Float16)v.y; h[2] = (_Float16)v.z; h[3] = (_Float16)v.w;
  *reinterpret_cast<f16x4v*>(reinterpret_cast<_Float16*>(eh) + (size_t)row * ND + lane * 4) = h;
}

// ---------------- kernel 3: fp16 MFMA GEMM screening + argmin (+2nd best) ----------------
// m97-structure: 64 rows x 128 codes per block; 4 waves (2x2); SINGLE-buffered 24KB LDS
// (A 8KB + B 16KB), two __syncthreads per K-step; 1024 blocks -> 4 blocks/CU.
// Codes are unit-norm -> argmin(dist) == argmax(dot); track top-2 via median identity.
#define MB 64
#define NB 128
#define BK 64
#define MARGIN 4e-4f   // in dot units; fp16 dot err <~2e-5 RMS

__launch_bounds__(256, 4)
__global__ void phase1_k(const unsigned short* __restrict__ zh_, const unsigned short* __restrict__ eh_,
                         int* __restrict__ best_idx, int* __restrict__ rcount,
                         int* __restrict__ rrows) {
  __shared__ __align__(16) _Float16 smem[4096 + 8192];  // A [64][64] + B [128][64] = 24576 B
  const _Float16* zh = reinterpret_cast<const _Float16*>(zh_);
  const _Float16* eh = reinterpret_cast<const _Float16*>(eh_);

  const int t = threadIdx.x;
  const int l = t & 63;
  const int wave = t >> 6;
  const int wm = wave & 1;   // row half
  const int wn = wave >> 1;  // code half
  const int l15 = l & 15, l4 = l >> 4;
  const int row0 = blockIdx.x * MB;

  const _Float16* aptr[2];
  int bofs[4];
  #pragma unroll
  for (int j = 0; j < 2; ++j) {
    const int o = wave * 1024 + j * 4096 + l * 16;
    const int r = o >> 7;
    const int sg = ((o >> 4) & 7) ^ (r & 7);
    aptr[j] = zh + (size_t)(row0 + r) * ND + sg * 8;
  }
  #pragma unroll
  for (int j = 0; j < 4; ++j) {
    const int o = wave * 1024 + j * 4096 + l * 16;
    const int r = o >> 7;
    const int sg = ((o >> 4) & 7) ^ (r & 7);
    bofs[j] = r * ND + sg * 8;
  }

  float m1[8], m2[8];
  int i1[8];
  #pragma unroll
  for (int s = 0; s < 8; ++s) { m1[s] = -3.4e38f; m2[s] = -3.4e38f; i1[s] = 0; }
  int cvec[4];
  #pragma unroll
  for (int nt = 0; nt < 4; ++nt) cvec[nt] = wn * 64 + nt * 16 + l15;

  f32x4 acc[2][4];

  for (int s = 0; s < 128; ++s) {
    const int ks = s & 3;
    if (ks == 0) {
      #pragma unroll
      for (int mt = 0; mt < 2; ++mt)
        #pragma unroll
        for (int nt = 0; nt < 4; ++nt) acc[mt][nt] = (f32x4){0.f, 0.f, 0.f, 0.f};
    }

    __syncthreads();
    {
      const int d0 = ks * BK;
      const size_t cofs = (size_t)(s >> 2) * (NB * ND);
      #pragma unroll
      for (int j = 0; j < 2; ++j)
        gll16(aptr[j] + d0, smem + wave * 512 + j * 2048);
      #pragma unroll
      for (int j = 0; j < 4; ++j)
        gll16(eh + cofs + bofs[j] + d0, smem + 4096 + wave * 512 + j * 2048);
    }
    __syncthreads();

    #pragma unroll
    for (int kk = 0; kk < 2; ++kk) {
      f16x8 aF[2], bF[4];
      #pragma unroll
      for (int mt = 0; mt < 2; ++mt) {
        const int ar = wm * 32 + mt * 16 + l15;
        const int sg = (kk * 4 + l4) ^ (ar & 7);
        aF[mt] = *reinterpret_cast<const f16x8*>(&smem[ar * BK + sg * 8]);
      }
      #pragma unroll
      for (int nt = 0; nt < 4; ++nt) {
        const int br = wn * 64 + nt * 16 + l15;
        const int sg = (kk * 4 + l4) ^ (br & 7);
        bF[nt] = *reinterpret_cast<const f16x8*>(&smem[4096 + br * BK + sg * 8]);
      }
      #pragma unroll
      for (int mt = 0; mt < 2; ++mt)
        #pragma unroll
        for (int nt = 0; nt < 4; ++nt)
          acc[mt][nt] = __builtin_amdgcn_mfma_f32_16x16x32_f16(aF[mt], bF[nt], acc[mt][nt], 0, 0, 0);
    }

    if (ks == 3) {
      const int cbase = (s >> 2) * NB;
      #pragma unroll
      for (int nt = 0; nt < 4; ++nt) {
        const int c = cbase + cvec[nt];
        #pragma unroll
        for (int mt = 0; mt < 2; ++mt) {
          #pragma unroll
          for (int r = 0; r < 4; ++r) {
            const float d = acc[mt][nt][r];
            const int slot = mt * 4 + r;
            m2[slot] = fmaxf(m2[slot], fminf(d, m1[slot]));
            if (d > m1[slot]) i1[slot] = c;
            m1[slot] = fmaxf(m1[slot], d);
          }
        }
      }
    }
  }

  float b1[8], b2[8];
  #pragma unroll
  for (int s = 0; s < 8; ++s) { b1[s] = -m1[s]; b2[s] = -m2[s]; }

  #pragma unroll
  for (int s = 0; s < 8; ++s) {
    #pragma unroll
    for (int m = 1; m < 16; m <<= 1) {
      const float ob1 = __shfl_xor(b1[s], m, 64);
      const float ob2 = __shfl_xor(b2[s], m, 64);
      const int oi1 = __shfl_xor(i1[s], m, 64);
      if (ob1 < b1[s] || (ob1 == b1[s] && oi1 < i1[s])) {
        b2[s] = fminf(b1[s], ob2);
        b1[s] = ob1; i1[s] = oi1;
      } else {
        b2[s] = fminf(b2[s], ob1);
      }
    }
  }

  __syncthreads();
  float* M1 = reinterpret_cast<float*>(smem);
  float* M2 = M1 + 128;
  int*   MI = (int*)(M1 + 256);
  if (l15 == 0) {
    #pragma unroll
    for (int s = 0; s < 8; ++s) {
      const int mt = s >> 2, r = s & 3;
      const int rl = wm * 32 + mt * 16 + l4 * 4 + r;
      M1[rl * 2 + wn] = b1[s];
      M2[rl * 2 + wn] = b2[s];
      MI[rl * 2 + wn] = i1[s];
    }
  }
  __syncthreads();
  if (t < MB) {
    float B1 = M1[t * 2], B2 = M2[t * 2];
    int I1 = MI[t * 2];
    const float y1 = M1[t * 2 + 1], y2 = M2[t * 2 + 1];
    const int yi = MI[t * 2 + 1];
    if (y1 < B1 || (y1 == B1 && yi < I1)) {
      B2 = fminf(B1, y2);
      B1 = y1; I1 = yi;
    } else {
      B2 = fminf(B2, y1);
    }
    const int row = row0 + t;
    best_idx[row] = I1;
    if (B2 - B1 < MARGIN) {
      const int pos = atomicAdd(rcount, 1);
      rrows[pos] = row;
    }
  }
}

// ---------------- kernel 4: fp32 staged rescan of flagged rows ----------------
// 8 rows x all 4096 codes per group. Codes staged in LDS 32 at a time (coalesced,
// register-prefetched); thread = one (code,row) pair; 4 independent fp32 FMA chains;
// no shuffles. Rows still ambiguous at MARGIN2 (fp32 precision) -> phase3.
#define TC 32
#define P2R 8
#define MARGIN2 1e-5f   // score units; fp32 dot err ~1.5e-7 RMS

__global__ void phase2_k(const float* __restrict__ z, const float* __restrict__ emb,
                         const float* __restrict__ e2_32, const double* __restrict__ inv64,
                         const int* __restrict__ rcount, const int* __restrict__ rrows,
                         int* __restrict__ best_idx, int* __restrict__ rcount2,
                         int* __restrict__ rrows2) {
  __shared__ float es[TC][ND + 4];     // 33.3KB, stride 260 -> banks 4*cl+d (conflict-free)
  __shared__ float znf[P2R][ND + 4];   // 8.3KB
  __shared__ float R1[P2R * TC], R2[P2R * TC];
  __shared__ int RIs[P2R * TC];
  const int t = threadIdx.x;
  const int cl = t >> 3, r = t & 7;
  int cnt = rcount[0];
  if (cnt > NROWS) cnt = NROWS;
  const int ngrp = (cnt + P2R - 1) / P2R;

  for (int g = blockIdx.x; g < ngrp; g += gridDim.x) {
    const int base = g * P2R;
    int nr = cnt - base;
    if (nr > P2R) nr = P2R;
    __syncthreads();   // previous group's reduce-readers done
    for (int i = t; i < P2R * ND; i += 256) {
      const int rr = i >> 8, d = i & (ND - 1);
      float v = 0.f;
      if (rr < nr) {
        const int row = rrows[base + rr];
        v = (float)((double)z[(size_t)row * ND + d] * inv64[row]);
      }
      znf[rr][d] = v;
    }
    float4 pf[8];
    #pragma unroll
    for (int k = 0; k < 8; ++k)
      pf[k] = *reinterpret_cast<const float4*>(emb + k * 1024 + t * 4);

    float B1 = 3.4e38f, B2 = 3.4e38f;
    int I1 = 0;
    for (int tile = 0; tile < NK / TC; ++tile) {
      __syncthreads();   // A: prev tile consumed (tile 0: zn writes now visible)
      #pragma unroll
      for (int k = 0; k < 8; ++k) {
        const int idx = k * 1024 + t * 4;
        *reinterpret_cast<float4*>(&es[idx >> 8][idx & (ND - 1)]) = pf[k];
      }
      if (tile + 1 < NK / TC) {
        const float* src = emb + (size_t)(tile + 1) * (TC * ND);
        #pragma unroll
        for (int k = 0; k < 8; ++k)
          pf[k] = *reinterpret_cast<const float4*>(src + k * 1024 + t * 4);
      }
      __syncthreads();   // B: es ready; prefetch stays in flight under compute
      const int c = tile * TC + cl;
      const float* er = &es[cl][0];
      const float* zr = &znf[r][0];
      float s0 = 0.f, s1 = 0.f, s2 = 0.f, s3 = 0.f;
      #pragma unroll 8
      for (int d = 0; d < ND; d += 4) {
        s0 = fmaf(zr[d + 0], er[d + 0], s0);
        s1 = fmaf(zr[d + 1], er[d + 1], s1);
        s2 = fmaf(zr[d + 2], er[d + 2], s2);
        s3 = fmaf(zr[d + 3], er[d + 3], s3);
      }
      const float sc = fmaf(-2.f, (s0 + s1) + (s2 + s3), e2_32[c]);
      if (sc < B1) { B2 = B1; B1 = sc; I1 = c; }   // codes ascending -> lowest idx on tie
      else if (sc < B2) B2 = sc;
    }
    R1[r * TC + cl] = B1; R2[r * TC + cl] = B2; RIs[r * TC + cl] = I1;
    __syncthreads();
    if (t < nr) {
      float b1 = R1[t * TC], b2 = R2[t * TC];
      int i1 = RIs[t * TC];
      for (int k = 1; k < TC; ++k) {
        const float o1 = R1[t * TC + k], o2 = R2[t * TC + k];
        const int oi = RIs[t * TC + k];
        if (o1 < b1 || (o1 == b1 && oi < i1)) { b2 = fminf(b1, o2); b1 = o1; i1 = oi; }
        else b2 = fminf(b2, o1);
      }
      const int row = rrows[base + t];
      if (b2 - b1 < MARGIN2) {
        const int pos = atomicAdd(rcount2, 1);
        if (pos < 4096) { rrows2[pos] = row; } else { best_idx[row] = i1; }
      } else {
        best_idx[row] = i1;
      }
    }
  }
}

// ---------------- kernel 5: exact fp64 recheck of phase2 survivors ----------------
// grid over (row e, 256-code chunk): block computes 256 fp64 scores, reduces, and
// atomicMin's a monotone packed key: (bits(score+2) & ~0xFFF) | idx.
__global__ void phase3_k(const float* __restrict__ z, const float* __restrict__ emb,
                         const double* __restrict__ e2_64, const double* __restrict__ inv64,
                         const int* __restrict__ rcount2, const int* __restrict__ rrows2,
                         unsigned long long* __restrict__ keys) {
  __shared__ double zn[ND];
  __shared__ double RB[256];
  __shared__ int RI[256];
  const int t = threadIdx.x;
  int cnt = rcount2[0];
  if (cnt > 4096) cnt = 4096;
  for (int idx = blockIdx.x; idx < cnt * 16; idx += gridDim.x) {
    const int e = idx >> 4, ch = idx & 15;
    const int row = rrows2[e];
    __syncthreads();
    zn[t] = (double)z[(size_t)row * ND + t] * inv64[row];
    __syncthreads();
    const int c = ch * 256 + t;
    const float* er = emb + (size_t)c * ND;
    double s0 = 0.0, s1 = 0.0, s2 = 0.0, s3 = 0.0;
    for (int d = 0; d < ND; d += 4) {
      const float4 ev = *reinterpret_cast<const float4*>(er + d);
      s0 += zn[d + 0] * (double)ev.x;
      s1 += zn[d + 1] * (double)ev.y;
      s2 += zn[d + 2] * (double)ev.z;
      s3 += zn[d + 3] * (double)ev.w;
    }
    RB[t] = e2_64[c] - 2.0 * ((s0 + s1) + (s2 + s3));
    RI[t] = c;
    __syncthreads();
    for (int off = 128; off; off >>= 1) {
      if (t < off) {
        const double sb = RB[t + off];
        const int si = RI[t + off];
        if (sb < RB[t] || (sb == RB[t] && si < RI[t])) { RB[t] = sb; RI[t] = si; }
      }
      __syncthreads();
    }
    if (t == 0) {
      const unsigned long long key =
          (((unsigned long long)__double_as_longlong(RB[0] + 2.0)) & ~0xFFFULL) |
          (unsigned long long)RI[0];
      atomicMin(&keys[e], key);
    }
  }
}

__global__ void fixup_k(const int* __restrict__ rcount2, const int* __restrict__ rrows2,
                        const unsigned long long* __restrict__ keys, int* __restrict__ best_idx) {
  int cnt = rcount2[0];
  if (cnt > 4096) cnt = 4096;
  for (int e = threadIdx.x + blockIdx.x * 256; e < cnt; e += 256 * gridDim.x)
    best_idx[rrows2[e]] = (int)(keys[e] & 0xFFFULL);
}

// ---------------- kernel 6: gather z_q, loss partials, histogram, index output ----------------
__global__ void gather_k(const float* __restrict__ z, const float* __restrict__ emb,
                         const int* __restrict__ best_idx, const double* __restrict__ inv64,
                         float* __restrict__ out, double* __restrict__ partials,
                         int* __restrict__ counts) {
  __shared__ double wsum[4];
  const int w = threadIdx.x >> 6, lane = threadIdx.x & 63;
  const int row = blockIdx.x * 4 + w;
  const int idx = best_idx[row];
  const double inv = inv64[row];
  const float4 zv = *reinterpret_cast<const float4*>(z + (size_t)row * ND + lane * 4);
  const float4 ev = *reinterpret_cast<const float4*>(emb + (size_t)idx * ND + lane * 4);
  *reinterpret_cast<float4*>(out + (size_t)row * ND + lane * 4) = ev;
  const double dx = (double)ev.x - (double)zv.x * inv;
  const double dy = (double)ev.y - (double)zv.y * inv;
  const double dz = (double)ev.z - (double)zv.z * inv;
  const double dw = (double)ev.w - (double)zv.w * inv;
  double s = dx * dx + dy * dy + dz * dz + dw * dw;
  #pragma unroll
  for (int m = 32; m; m >>= 1) s += __shfl_xor(s, m, 64);
  if (lane == 0) {
    wsum[w] = s;
    atomicAdd(&counts[idx], 1);
    out[IDX_OFF + row] = (float)idx;
  }
  __syncthreads();
  if (threadIdx.x == 0) partials[blockIdx.x] = wsum[0] + wsum[1] + wsum[2] + wsum[3];
}

// ---------------- kernel 7: scalars (losses + perplexity) ----------------
__global__ void finalize_k(const double* __restrict__ partials, const int* __restrict__ counts,
                           float* __restrict__ out) {
  __shared__ double red[256];
  const int t = threadIdx.x;
  double s = 0.0;
  for (int k = 0; k < 64; ++k) s += partials[t + 256 * k];
  red[t] = s;
  __syncthreads();
  for (int off = 128; off; off >>= 1) {
    if (t < off) red[t] += red[t + off];
    __syncthreads();
  }
  const double c = red[0] / (double)M_OUT;
  __syncthreads();
  double h = 0.0;
  for (int k = 0; k < 16; ++k) {
    const double p = (double)counts[t * 16 + k] * (1.0 / 65536.0);
    h += p * log(p + 1e-10);
  }
  red[t] = h;
  __syncthreads();
  for (int off = 128; off; off >>= 1) {
    if (t < off) red[t] += red[t + off];
    __syncthreads();
  }
  if (t == 0) {
    const double perp = exp(-red[0]);
    out[M_OUT + 0] = (float)(c + 0.25 * c);
    out[M_OUT + 1] = (float)c;
    out[M_OUT + 2] = (float)c;
    out[M_OUT + 3] = (float)perp;
  }
}

extern "C" void kernel_launch(void* const* d_in, const int* in_sizes, int n_in,
                              void* d_out, int out_size, void* d_ws, size_t ws_size,
                              hipStream_t stream) {
  const float* z = (const float*)d_in[0];
  const float* emb = (const float*)d_in[1];
  float* out = (float*)d_out;
  char* ws = (char*)d_ws;
  double* inv64   = (double*)(ws + WS_INV64);
  double* e2_64   = (double*)(ws + WS_E2_64);
  float*  e2_32   = (float*)(ws + WS_E2_32);
  unsigned short* eh = (unsigned short*)(ws + WS_EH);
  int*    best_i  = (int*)(ws + WS_BESTIDX);
  int*    counts  = (int*)(ws + WS_COUNTS);
  int*    rcount  = (int*)(ws + WS_RCOUNT);
  int*    rrows   = (int*)(ws + WS_RROWS);
  int*    rcount2 = (int*)(ws + WS_RCNT2);
  int*    rrows2  = (int*)(ws + WS_RROWS2);
  unsigned long long* keys = (unsigned long long*)(ws + WS_KEYS);
  double* partials = (double*)(ws + WS_PART);
  unsigned short* zh = (unsigned short*)d_out;  // [65536][256] f16, overwritten by gather_k

  hipMemsetAsync(ws + WS_COUNTS, 0, 16 * 1024 + 16, stream);  // counts + rcount
  hipMemsetAsync(ws + WS_RCNT2, 0, 16, stream);               // rcount2
  hipMemsetAsync(ws + WS_KEYS, 0xFF, 32 * 1024, stream);      // keys = +inf
  rownorm_k<<<NROWS / 4, 256, 0, stream>>>(z, inv64, zh);
  embnorm_k<<<NK / 4, 256, 0, stream>>>(emb, e2_64, e2_32, eh);
  phase1_k<<<NROWS / MB, 256, 0, stream>>>(zh, eh, best_i, rcount, rrows);
  phase2_k<<<768, 256, 0, stream>>>(z, emb, e2_32, inv64, rcount, rrows, best_i, rcount2, rrows2);
  phase3_k<<<1024, 256, 0, stream>>>(z, emb, e2_64, inv64, rcount2, rrows2, keys);
  fixup_k<<<16, 256, 0, stream>>>(rcount2, rrows2, keys, best_i);
  gather_k<<<NROWS / 4, 256, 0, stream>>>(z, emb, best_i, inv64, out, partials, counts);
  finalize_k<<<1, 256, 0, stream>>>(partials, counts, out);
}

// Round 6
// 481.384 us; speedup vs baseline: 1.9002x; 1.9002x over previous
//
#include <hip/hip_runtime.h>
#include <cstdint>
#include <cstddef>

#define ND 256          // embedding dim
#define NK 4096         // num codes
#define NROWS 65536     // 32*2048
#define M_OUT 16777216  // NROWS*ND
#define IDX_OFF (M_OUT + 4)

// ---------------- workspace layout (bytes) ----------------
#define WS_INV64   0                         // double[65536]  512KB
#define WS_E2_64   (512*1024)                // double[4096]   32KB
#define WS_EH      (WS_E2_64 + 32*1024)      // f16[1M]        2MB
#define WS_BESTIDX (WS_EH + 2*1024*1024)     // int[65536]     256KB
#define WS_COUNTS  (WS_BESTIDX + 256*1024)   // int[4096]      16KB
#define WS_RCOUNT  (WS_COUNTS + 16*1024)     // int[1] + pad   16B
#define WS_RROWS   (WS_RCOUNT + 16)          // int[65536]     256KB
#define WS_KEYS    (WS_RROWS + 256*1024)     // u64[65536]     512KB
#define WS_PART    (WS_KEYS + 512*1024)      // double[16384]  128KB

typedef _Float16 f16x8 __attribute__((ext_vector_type(8)));
typedef _Float16 f16x4v __attribute__((ext_vector_type(4)));
typedef __attribute__((ext_vector_type(4))) float f32x4;

// async 16B global->LDS (direct-to-shared DMA); lds dest must be wave-uniform base
__device__ __forceinline__ void gll16(const void* g, void* l) {
  __builtin_amdgcn_global_load_lds(
      (const __attribute__((address_space(1))) unsigned int*)g,
      (__attribute__((address_space(3))) unsigned int*)l, 16, 0, 0);
}

// ---------------- kernel 1: row norms + normalized fp16 plane ----------------
__global__ void rownorm_k(const float* __restrict__ z, double* __restrict__ inv64,
                          unsigned short* __restrict__ zh) {
  const int w = threadIdx.x >> 6, lane = threadIdx.x & 63;
  const int row = blockIdx.x * 4 + w;
  const float4 v = *reinterpret_cast<const float4*>(z + (size_t)row * ND + lane * 4);
  double s = (double)v.x * v.x + (double)v.y * v.y + (double)v.z * v.z + (double)v.w * v.w;
  #pragma unroll
  for (int m = 32; m; m >>= 1) s += __shfl_xor(s, m, 64);
  double nrm = sqrt(s);
  if (nrm < 1e-12) nrm = 1e-12;
  const double inv = 1.0 / nrm;
  if (lane == 0) inv64[row] = inv;
  f16x4v h;
  h[0] = (_Float16)(float)(v.x * inv);
  h[1] = (_Float16)(float)(v.y * inv);
  h[2] = (_Float16)(float)(v.z * inv);
  h[3] = (_Float16)(float)(v.w * inv);
  *reinterpret_cast<f16x4v*>(reinterpret_cast<_Float16*>(zh) + (size_t)row * ND + lane * 4) = h;
}

// ---------------- kernel 2: code norms (fp64, for exact recheck) + fp16 plane ----------------
__global__ void embnorm_k(const float* __restrict__ e, double* __restrict__ e2_64,
                          unsigned short* __restrict__ eh) {
  const int w = threadIdx.x >> 6, lane = threadIdx.x & 63;
  const int row = blockIdx.x * 4 + w;
  const float4 v = *reinterpret_cast<const float4*>(e + (size_t)row * ND + lane * 4);
  double s = (double)v.x * v.x + (double)v.y * v.y + (double)v.z * v.z + (double)v.w * v.w;
  #pragma unroll
  for (int m = 32; m; m >>= 1) s += __shfl_xor(s, m, 64);
  if (lane == 0) e2_64[row] = s;
  f16x4v h;
  h[0] = (_Float16)v.x; h[1] = (_Float16)v.y; h[2] = (_Float16)v.z; h[3] = (_Float16)v.w;
  *reinterpret_cast<f16x4v*>(reinterpret_cast<_Float16*>(eh) + (size_t)row * ND + lane * 4) = h;
}

// ---------------- kernel 3: fp16 MFMA GEMM screening + argmin (+2nd best) ----------------
// m97-structure: 64 rows x 128 codes per block; 4 waves (2x2); SINGLE-buffered 24KB LDS
// (A 8KB + B 16KB), two __syncthreads per K-step; 1024 blocks -> 4 blocks/CU.
// Codes are unit-norm -> argmin(dist) == argmax(dot); track top-2 via median identity.
#define MB 64
#define NB 128
#define BK 64
// fp16 screen dot-err sigma ~1e-5 (bounded RNE sum); 1.5e-4 >= 7 sigma even at 2x model.
// Empirical gap law P(gap<m) ~ m/1.75e-3 -> cnt ~ 5.6k flagged rows.
#define MARGIN 1.5e-4f

__launch_bounds__(256, 4)
__global__ void phase1_k(const unsigned short* __restrict__ zh_, const unsigned short* __restrict__ eh_,
                         int* __restrict__ best_idx, int* __restrict__ rcount,
                         int* __restrict__ rrows) {
  __shared__ __align__(16) _Float16 smem[4096 + 8192];  // A [64][64] + B [128][64] = 24576 B
  const _Float16* zh = reinterpret_cast<const _Float16*>(zh_);
  const _Float16* eh = reinterpret_cast<const _Float16*>(eh_);

  const int t = threadIdx.x;
  const int l = t & 63;
  const int wave = t >> 6;
  const int wm = wave & 1;   // row half
  const int wn = wave >> 1;  // code half
  const int l15 = l & 15, l4 = l >> 4;
  const int row0 = blockIdx.x * MB;

  const _Float16* aptr[2];
  int bofs[4];
  #pragma unroll
  for (int j = 0; j < 2; ++j) {
    const int o = wave * 1024 + j * 4096 + l * 16;
    const int r = o >> 7;
    const int sg = ((o >> 4) & 7) ^ (r & 7);
    aptr[j] = zh + (size_t)(row0 + r) * ND + sg * 8;
  }
  #pragma unroll
  for (int j = 0; j < 4; ++j) {
    const int o = wave * 1024 + j * 4096 + l * 16;
    const int r = o >> 7;
    const int sg = ((o >> 4) & 7) ^ (r & 7);
    bofs[j] = r * ND + sg * 8;
  }

  float m1[8], m2[8];
  int i1[8];
  #pragma unroll
  for (int s = 0; s < 8; ++s) { m1[s] = -3.4e38f; m2[s] = -3.4e38f; i1[s] = 0; }
  int cvec[4];
  #pragma unroll
  for (int nt = 0; nt < 4; ++nt) cvec[nt] = wn * 64 + nt * 16 + l15;

  f32x4 acc[2][4];

  for (int s = 0; s < 128; ++s) {
    const int ks = s & 3;
    if (ks == 0) {
      #pragma unroll
      for (int mt = 0; mt < 2; ++mt)
        #pragma unroll
        for (int nt = 0; nt < 4; ++nt) acc[mt][nt] = (f32x4){0.f, 0.f, 0.f, 0.f};
    }

    __syncthreads();
    {
      const int d0 = ks * BK;
      const size_t cofs = (size_t)(s >> 2) * (NB * ND);
      #pragma unroll
      for (int j = 0; j < 2; ++j)
        gll16(aptr[j] + d0, smem + wave * 512 + j * 2048);
      #pragma unroll
      for (int j = 0; j < 4; ++j)
        gll16(eh + cofs + bofs[j] + d0, smem + 4096 + wave * 512 + j * 2048);
    }
    __syncthreads();

    #pragma unroll
    for (int kk = 0; kk < 2; ++kk) {
      f16x8 aF[2], bF[4];
      #pragma unroll
      for (int mt = 0; mt < 2; ++mt) {
        const int ar = wm * 32 + mt * 16 + l15;
        const int sg = (kk * 4 + l4) ^ (ar & 7);
        aF[mt] = *reinterpret_cast<const f16x8*>(&smem[ar * BK + sg * 8]);
      }
      #pragma unroll
      for (int nt = 0; nt < 4; ++nt) {
        const int br = wn * 64 + nt * 16 + l15;
        const int sg = (kk * 4 + l4) ^ (br & 7);
        bF[nt] = *reinterpret_cast<const f16x8*>(&smem[4096 + br * BK + sg * 8]);
      }
      #pragma unroll
      for (int mt = 0; mt < 2; ++mt)
        #pragma unroll
        for (int nt = 0; nt < 4; ++nt)
          acc[mt][nt] = __builtin_amdgcn_mfma_f32_16x16x32_f16(aF[mt], bF[nt], acc[mt][nt], 0, 0, 0);
    }

    if (ks == 3) {
      const int cbase = (s >> 2) * NB;
      #pragma unroll
      for (int nt = 0; nt < 4; ++nt) {
        const int c = cbase + cvec[nt];
        #pragma unroll
        for (int mt = 0; mt < 2; ++mt) {
          #pragma unroll
          for (int r = 0; r < 4; ++r) {
            const float d = acc[mt][nt][r];
            const int slot = mt * 4 + r;
            m2[slot] = fmaxf(m2[slot], fminf(d, m1[slot]));
            if (d > m1[slot]) i1[slot] = c;
            m1[slot] = fmaxf(m1[slot], d);
          }
        }
      }
    }
  }

  float b1[8], b2[8];
  #pragma unroll
  for (int s = 0; s < 8; ++s) { b1[s] = -m1[s]; b2[s] = -m2[s]; }

  #pragma unroll
  for (int s = 0; s < 8; ++s) {
    #pragma unroll
    for (int m = 1; m < 16; m <<= 1) {
      const float ob1 = __shfl_xor(b1[s], m, 64);
      const float ob2 = __shfl_xor(b2[s], m, 64);
      const int oi1 = __shfl_xor(i1[s], m, 64);
      if (ob1 < b1[s] || (ob1 == b1[s] && oi1 < i1[s])) {
        b2[s] = fminf(b1[s], ob2);
        b1[s] = ob1; i1[s] = oi1;
      } else {
        b2[s] = fminf(b2[s], ob1);
      }
    }
  }

  __syncthreads();
  float* M1 = reinterpret_cast<float*>(smem);
  float* M2 = M1 + 128;
  int*   MI = (int*)(M1 + 256);
  if (l15 == 0) {
    #pragma unroll
    for (int s = 0; s < 8; ++s) {
      const int mt = s >> 2, r = s & 3;
      const int rl = wm * 32 + mt * 16 + l4 * 4 + r;
      M1[rl * 2 + wn] = b1[s];
      M2[rl * 2 + wn] = b2[s];
      MI[rl * 2 + wn] = i1[s];
    }
  }
  __syncthreads();
  if (t < MB) {
    float B1 = M1[t * 2], B2 = M2[t * 2];
    int I1 = MI[t * 2];
    const float y1 = M1[t * 2 + 1], y2 = M2[t * 2 + 1];
    const int yi = MI[t * 2 + 1];
    if (y1 < B1 || (y1 == B1 && yi < I1)) {
      B2 = fminf(B1, y2);
      B1 = y1; I1 = yi;
    } else {
      B2 = fminf(B2, y1);
    }
    const int row = row0 + t;
    best_idx[row] = I1;
    if (B2 - B1 < MARGIN) {
      const int pos = atomicAdd(rcount, 1);
      rrows[pos] = row;
    }
  }
}

// ---------------- kernel 4: exact fp64 recheck, chunked, atomicMin packed-key merge ----
// Job = (group of 8 flagged rows) x (1024-code chunk). d-outer loop: the 4 code-streams
// per thread share each zn LDS broadcast (wave-uniform read -> conflict-free).
// Per-row winner merged across chunks via atomicMin on (bits(score+2) & ~0xFFF) | idx
// (monotone packed key, proven in R5's phase3): equal quantized scores -> lowest idx.
#define P2R 8
#define CCH 1024
#define NCH (NK / CCH)   // 4

__launch_bounds__(256, 4)
__global__ void phase2_k(const float* __restrict__ z, const float* __restrict__ emb,
                         const double* __restrict__ e2_64, const double* __restrict__ inv64,
                         const int* __restrict__ rcount, const int* __restrict__ rrows,
                         unsigned long long* __restrict__ keys) {
  __shared__ double zn[P2R][ND];   // 16KB
  const int t = threadIdx.x;
  const int lane = t & 63;
  int cnt = rcount[0];
  if (cnt > NROWS) cnt = NROWS;
  const int ngrp = (cnt + P2R - 1) / P2R;
  const int njob = ngrp * NCH;

  for (int job = blockIdx.x; job < njob; job += gridDim.x) {
    const int g = job >> 2, ch = job & (NCH - 1);
    const int base = g * P2R;
    int nr = cnt - base;
    if (nr > P2R) nr = P2R;
    __syncthreads();   // previous job's zn readers done
    for (int i = t; i < P2R * ND; i += 256) {
      const int rr = i >> 8, d = i & (ND - 1);
      double v = 0.0;
      if (rr < nr) {
        const int row = rrows[base + rr];
        v = (double)z[(size_t)row * ND + d] * inv64[row];
      }
      zn[rr][d] = v;
    }
    __syncthreads();

    const int c0 = ch * CCH + t * 4;   // 4 ascending codes per thread
    double acc[4][P2R];
    #pragma unroll
    for (int k = 0; k < 4; ++k)
      #pragma unroll
      for (int r = 0; r < P2R; ++r) acc[k][r] = 0.0;

    const float* e0 = emb + (size_t)c0 * ND;
    for (int d = 0; d < ND; d += 4) {
      float4 ev[4];
      #pragma unroll
      for (int k = 0; k < 4; ++k)
        ev[k] = *reinterpret_cast<const float4*>(e0 + k * ND + d);
      #pragma unroll
      for (int r = 0; r < P2R; ++r) {
        const double z0 = zn[r][d], z1 = zn[r][d + 1], z2 = zn[r][d + 2], z3 = zn[r][d + 3];
        #pragma unroll
        for (int k = 0; k < 4; ++k)
          acc[k][r] += z0 * (double)ev[k].x + z1 * (double)ev[k].y +
                       z2 * (double)ev[k].z + z3 * (double)ev[k].w;
      }
    }

    double e2v[4];
    #pragma unroll
    for (int k = 0; k < 4; ++k) e2v[k] = e2_64[c0 + k];

    #pragma unroll
    for (int r = 0; r < P2R; ++r) {
      unsigned long long mk = 0xFFFFFFFFFFFFFFFFULL;
      #pragma unroll
      for (int k = 0; k < 4; ++k) {
        const double sc = e2v[k] - 2.0 * acc[k][r] + 2.0;   // > 0 -> bit-order == numeric
        const unsigned long long key =
            (((unsigned long long)__double_as_longlong(sc)) & ~0xFFFULL) |
            (unsigned long long)(c0 + k);
        mk = key < mk ? key : mk;
      }
      #pragma unroll
      for (int m = 1; m < 64; m <<= 1) {
        const unsigned long long om = __shfl_xor(mk, m, 64);
        mk = om < mk ? om : mk;
      }
      if (lane == 0 && r < nr) atomicMin(&keys[base + r], mk);
    }
  }
}

// ---------------- kernel 5: keys -> best_idx for flagged rows ----------------
__global__ void fixup_k(const int* __restrict__ rcount, const int* __restrict__ rrows,
                        const unsigned long long* __restrict__ keys, int* __restrict__ best_idx) {
  int cnt = rcount[0];
  if (cnt > NROWS) cnt = NROWS;
  for (int e = threadIdx.x + blockIdx.x * 256; e < cnt; e += 256 * gridDim.x)
    best_idx[rrows[e]] = (int)(keys[e] & 0xFFFULL);
}

// ---------------- kernel 6: gather z_q, loss partials, histogram, index output ----------------
__global__ void gather_k(const float* __restrict__ z, const float* __restrict__ emb,
                         const int* __restrict__ best_idx, const double* __restrict__ inv64,
                         float* __restrict__ out, double* __restrict__ partials,
                         int* __restrict__ counts) {
  __shared__ double wsum[4];
  const int w = threadIdx.x >> 6, lane = threadIdx.x & 63;
  const int row = blockIdx.x * 4 + w;
  const int idx = best_idx[row];
  const double inv = inv64[row];
  const float4 zv = *reinterpret_cast<const float4*>(z + (size_t)row * ND + lane * 4);
  const float4 ev = *reinterpret_cast<const float4*>(emb + (size_t)idx * ND + lane * 4);
  *reinterpret_cast<float4*>(out + (size_t)row * ND + lane * 4) = ev;
  const double dx = (double)ev.x - (double)zv.x * inv;
  const double dy = (double)ev.y - (double)zv.y * inv;
  const double dz = (double)ev.z - (double)zv.z * inv;
  const double dw = (double)ev.w - (double)zv.w * inv;
  double s = dx * dx + dy * dy + dz * dz + dw * dw;
  #pragma unroll
  for (int m = 32; m; m >>= 1) s += __shfl_xor(s, m, 64);
  if (lane == 0) {
    wsum[w] = s;
    atomicAdd(&counts[idx], 1);
    out[IDX_OFF + row] = (float)idx;
  }
  __syncthreads();
  if (threadIdx.x == 0) partials[blockIdx.x] = wsum[0] + wsum[1] + wsum[2] + wsum[3];
}

// ---------------- kernel 7: scalars (losses + perplexity) ----------------
__global__ void finalize_k(const double* __restrict__ partials, const int* __restrict__ counts,
                           float* __restrict__ out) {
  __shared__ double red[256];
  const int t = threadIdx.x;
  double s = 0.0;
  for (int k = 0; k < 64; ++k) s += partials[t + 256 * k];
  red[t] = s;
  __syncthreads();
  for (int off = 128; off; off >>= 1) {
    if (t < off) red[t] += red[t + off];
    __syncthreads();
  }
  const double c = red[0] / (double)M_OUT;
  __syncthreads();
  double h = 0.0;
  for (int k = 0; k < 16; ++k) {
    const double p = (double)counts[t * 16 + k] * (1.0 / 65536.0);
    h += p * log(p + 1e-10);
  }
  red[t] = h;
  __syncthreads();
  for (int off = 128; off; off >>= 1) {
    if (t < off) red[t] += red[t + off];
    __syncthreads();
  }
  if (t == 0) {
    const double perp = exp(-red[0]);
    out[M_OUT + 0] = (float)(c + 0.25 * c);
    out[M_OUT + 1] = (float)c;
    out[M_OUT + 2] = (float)c;
    out[M_OUT + 3] = (float)perp;
  }
}

extern "C" void kernel_launch(void* const* d_in, const int* in_sizes, int n_in,
                              void* d_out, int out_size, void* d_ws, size_t ws_size,
                              hipStream_t stream) {
  const float* z = (const float*)d_in[0];
  const float* emb = (const float*)d_in[1];
  float* out = (float*)d_out;
  char* ws = (char*)d_ws;
  double* inv64   = (double*)(ws + WS_INV64);
  double* e2_64   = (double*)(ws + WS_E2_64);
  unsigned short* eh = (unsigned short*)(ws + WS_EH);
  int*    best_i  = (int*)(ws + WS_BESTIDX);
  int*    counts  = (int*)(ws + WS_COUNTS);
  int*    rcount  = (int*)(ws + WS_RCOUNT);
  int*    rrows   = (int*)(ws + WS_RROWS);
  unsigned long long* keys = (unsigned long long*)(ws + WS_KEYS);
  double* partials = (double*)(ws + WS_PART);
  unsigned short* zh = (unsigned short*)d_out;  // [65536][256] f16, overwritten by gather_k

  hipMemsetAsync(ws + WS_COUNTS, 0, 16 * 1024 + 16, stream);  // counts + rcount
  hipMemsetAsync(ws + WS_KEYS, 0xFF, 512 * 1024, stream);     // keys = +inf
  rownorm_k<<<NROWS / 4, 256, 0, stream>>>(z, inv64, zh);
  embnorm_k<<<NK / 4, 256, 0, stream>>>(emb, e2_64, eh);
  phase1_k<<<NROWS / MB, 256, 0, stream>>>(zh, eh, best_i, rcount, rrows);
  phase2_k<<<2048, 256, 0, stream>>>(z, emb, e2_64, inv64, rcount, rrows, keys);
  fixup_k<<<64, 256, 0, stream>>>(rcount, rrows, keys, best_i);
  gather_k<<<NROWS / 4, 256, 0, stream>>>(z, emb, best_i, inv64, out, partials, counts);
  finalize_k<<<1, 256, 0, stream>>>(partials, counts, out);
}